// Round 2
// baseline (797.838 us; speedup 1.0000x reference)
//
#include <hip/hip_runtime.h>
#include <math.h>

#define NN 50000
#define NE 800000
#define NTILE2 6250   // NE / 128
#define NBLK 196      // ceil(NN / 256)

typedef __bf16 bf16x4 __attribute__((ext_vector_type(4)));
typedef __bf16 bf16x8 __attribute__((ext_vector_type(8)));
typedef float  f32x4  __attribute__((ext_vector_type(4)));

// softplus via hw v_exp_f32 / v_log_f32
__device__ __forceinline__ float softplus_f(float v) {
    const float t = __expf(-fabsf(v));
    return fmaxf(v, 0.f) + __logf(1.f + t);
}

// ---------------- x fp32 -> bf16 prep (6.4 MB, L2/L3-resident for gathers) ----
__global__ void k_prep(const float* __restrict__ x, __bf16* __restrict__ xb) {
    const int i = blockIdx.x * 256 + threadIdx.x;   // f32x4 items
    if (i < NN * 16) {
        const f32x4 v = *(const f32x4*)(x + (size_t)i * 4);
        bf16x4 b;
        b[0]=(__bf16)v[0]; b[1]=(__bf16)v[1]; b[2]=(__bf16)v[2]; b[3]=(__bf16)v[3];
        *(bf16x4*)(xb + (size_t)i * 4) = b;
    }
}

// ---------------- CSR build ----------------
__global__ void k_zero(int* deg) {
    int i = blockIdx.x * blockDim.x + threadIdx.x;
    if (i < NN) deg[i] = 0;
}

__global__ void k_hist(const int* __restrict__ ei, int* __restrict__ deg) {
    int e = blockIdx.x * blockDim.x + threadIdx.x;
    if (e < NE) atomicAdd(&deg[ei[NE + e]], 1);
}

__global__ void k_bsum(const int* __restrict__ deg, int* __restrict__ bsum) {
    __shared__ int ws4[4];
    const int tid = threadIdx.x;
    const int i = blockIdx.x * 256 + tid;
    int v = (i < NN) ? deg[i] : 0;
    #pragma unroll
    for (int off = 1; off < 64; off <<= 1) v += __shfl_xor(v, off);
    if ((tid & 63) == 0) ws4[tid >> 6] = v;
    __syncthreads();
    if (tid == 0) bsum[blockIdx.x] = ws4[0] + ws4[1] + ws4[2] + ws4[3];
}

__global__ void k_bscan(const int* __restrict__ bsum, int* __restrict__ boff) {
    __shared__ int wsum[4];
    const int tid = threadIdx.x, lane = tid & 63, wid = tid >> 6;
    const int v = (tid < NBLK) ? bsum[tid] : 0;
    int s = v;
    #pragma unroll
    for (int off = 1; off < 64; off <<= 1) {
        int t = __shfl_up(s, off);
        if (lane >= off) s += t;
    }
    if (lane == 63) wsum[wid] = s;
    __syncthreads();
    int add = 0;
    #pragma unroll
    for (int q = 0; q < 4; ++q) add += (q < wid) ? wsum[q] : 0;
    if (tid < NBLK) boff[tid] = (s + add) - v;   // exclusive prefix
}

__global__ void k_apply(const int* __restrict__ deg, const int* __restrict__ boff,
                        int* __restrict__ rowptr, int* __restrict__ cursor) {
    __shared__ int wsum[4];
    const int tid = threadIdx.x, lane = tid & 63, wid = tid >> 6;
    const int i = blockIdx.x * 256 + tid;
    const int v = (i < NN) ? deg[i] : 0;
    int s = v;
    #pragma unroll
    for (int off = 1; off < 64; off <<= 1) {
        int t = __shfl_up(s, off);
        if (lane >= off) s += t;
    }
    if (lane == 63) wsum[wid] = s;
    __syncthreads();
    int add = boff[blockIdx.x];
    #pragma unroll
    for (int q = 0; q < 4; ++q) add += (q < wid) ? wsum[q] : 0;
    const int incl = s + add;
    if (i < NN) { rowptr[i + 1] = incl; cursor[i] = incl - v; }
    if (i == 0) rowptr[0] = 0;
}

__global__ void k_scatter(const int* __restrict__ ei, int* __restrict__ cursor,
                          int* __restrict__ eidx) {
    int e = blockIdx.x * blockDim.x + threadIdx.x;
    if (e < NE) {
        int d = ei[NE + e];
        int p = atomicAdd(&cursor[d], 1);
        eidx[p] = e;
    }
}

// ---------------- edge kernel: strain + msg GEMM + edge GEMM ----------------
// 512 threads / 128 edges per tile (8 waves x 16 edges). LDS 77.3KB -> 2
// blocks/CU = 16 waves/CU (50% occ). 2 barriers/tile:
//  - edge indices loaded directly per staging thread (L1 broadcast) -- no
//    sSrc/sDst staging + barrier.
//  - A2 msg-overlay is wave-private: in-wave lgkmcnt ordering suffices, no
//    __syncthreads between msg epilogue and edge GEMM (sched_barrier pins it).
// A row layout (k): [0..63]=x_src [64..127]=x_dst [128..191]=edge_attr;
// strain folded in as rank-1 accumulator init. Stride 200 elems (400B) for
// bank spread. USE_XB: x pre-converted to bf16 (halves gather bytes, no cvt).
template<bool USE_XB>
__global__ __launch_bounds__(512, 2) void k_edge(
    const float* __restrict__ x, const __bf16* __restrict__ xb,
    const int* __restrict__ ei,
    const float* __restrict__ ea, const float* __restrict__ r2,
    const float* __restrict__ dinit, const float* __restrict__ Wmsg,
    const float* __restrict__ bmsg, const float* __restrict__ Wedge,
    const float* __restrict__ bedge,
    float* __restrict__ out_edge, float* __restrict__ out_msg,
    float* __restrict__ out_strain)
{
    __shared__ __bf16 sWm[64 * 200];    // Wmsg^T (k=0..191), row n, stride 200
    __shared__ __bf16 sA [128 * 200];   // 128 edge rows, stride 200
    __shared__ float  sStrain[128];

    const int tid  = threadIdx.x;
    const int lane = tid & 63;
    const int wid  = tid >> 6;     // wave 0..7, owns edges wid*16..wid*16+15
    const int col  = lane & 15;
    const int quad = lane >> 4;

    // ---- stage transposed Wmsg once per (persistent) block ----
    {
        const int n = tid & 63, kg = tid >> 6;
        for (int k = kg; k < 192; k += 8) {
            // original W rows: 0-63 x_j | 64-127 x_i | 128 strain | 129-192 ea
            float v = (k < 128) ? Wmsg[k * 64 + n] : Wmsg[(k + 1) * 64 + n];
            sWm[n * 200 + k] = (__bf16)v;
        }
    }
    // ---- Wedge^T B-fragments in registers (once per block) ----
    bf16x8 weF[2][4];
    #pragma unroll
    for (int kc = 0; kc < 2; ++kc)
        #pragma unroll
        for (int nt = 0; nt < 4; ++nt) {
            bf16x8 f;
            #pragma unroll
            for (int j = 0; j < 8; ++j)
                f[j] = (__bf16)Wedge[(kc * 32 + quad * 8 + j) * 64 + nt * 16 + col];
            weF[kc][nt] = f;
        }
    float bm[4], be[4], wst[4];
    #pragma unroll
    for (int nt = 0; nt < 4; ++nt) {
        bm[nt]  = bmsg[nt * 16 + col];
        be[nt]  = bedge[nt * 16 + col];
        wst[nt] = Wmsg[128 * 64 + nt * 16 + col];   // strain weight row (fp32)
    }

    for (int tile = blockIdx.x; tile < NTILE2; tile += gridDim.x) {
        const int e0 = tile * 128;

        // ---- stage x_src / x_dst (gathers; per-thread index loads) ----
        if constexpr (USE_XB) {
            #pragma unroll
            for (int it = 0; it < 2; ++it) {
                const int i = tid + it * 512;     // 0..1023
                const int e = i >> 3, c = i & 7;  // 128 edges x 8 bf16x8-chunks
                const int s = ei[e0 + e], d = ei[NE + e0 + e];
                const bf16x8 vj = *(const bf16x8*)(xb + (size_t)s * 64 + c * 8);
                const bf16x8 vi = *(const bf16x8*)(xb + (size_t)d * 64 + c * 8);
                *(bf16x8*)&sA[e * 200 +      c * 8] = vj;
                *(bf16x8*)&sA[e * 200 + 64 + c * 8] = vi;
            }
        } else {
            #pragma unroll
            for (int it = 0; it < 4; ++it) {
                const int i = tid + it * 512;      // 0..2047
                const int e = i >> 4, c = i & 15;  // 128 edges x 16 f32x4-chunks
                const int s = ei[e0 + e], d = ei[NE + e0 + e];
                const f32x4 xj = *(const f32x4*)(x + (size_t)s * 64 + c * 4);
                const f32x4 xi = *(const f32x4*)(x + (size_t)d * 64 + c * 4);
                bf16x4 a, b;
                a[0]=(__bf16)xj[0]; a[1]=(__bf16)xj[1]; a[2]=(__bf16)xj[2]; a[3]=(__bf16)xj[3];
                b[0]=(__bf16)xi[0]; b[1]=(__bf16)xi[1]; b[2]=(__bf16)xi[2]; b[3]=(__bf16)xi[3];
                *(bf16x4*)&sA[e * 200 +      c * 4] = a;
                *(bf16x4*)&sA[e * 200 + 64 + c * 4] = b;
            }
        }
        // ---- stage edge_attr (single-use stream: nontemporal) ----
        #pragma unroll
        for (int it = 0; it < 4; ++it) {
            const int i = tid + it * 512;      // 0..2047
            const int e = i >> 4, c = i & 15;
            const f32x4 ev = __builtin_nontemporal_load(
                                 (const f32x4*)(ea + (size_t)(e0 + e) * 64 + c * 4));
            bf16x4 d;
            d[0]=(__bf16)ev[0]; d[1]=(__bf16)ev[1]; d[2]=(__bf16)ev[2]; d[3]=(__bf16)ev[3];
            *(bf16x4*)&sA[e * 200 + 128 + c * 4] = d;
        }
        if (tid < 128) {
            const float rx = r2[(size_t)(e0 + tid) * 2];
            const float ry = r2[(size_t)(e0 + tid) * 2 + 1];
            const float di = dinit[e0 + tid];
            const float st = (sqrtf(rx * rx + ry * ry) - di) / di;
            sStrain[tid] = st;
            __builtin_nontemporal_store(st, &out_strain[e0 + tid]);
        }
        __syncthreads();

        // ---- msg = softplus(A @ Wm + strain*w128 + b): 6 k-chunks x 4 n-tiles
        f32x4 acc[4];
        const int r0 = wid * 16 + quad * 4;
        #pragma unroll
        for (int nt = 0; nt < 4; ++nt)
            #pragma unroll
            for (int rg = 0; rg < 4; ++rg)
                acc[nt][rg] = sStrain[r0 + rg] * wst[nt];   // rank-1 strain term

        const int abase = (wid * 16 + col) * 200 + quad * 8;
        #pragma unroll
        for (int kc = 0; kc < 6; ++kc) {
            const bf16x8 af = *(const bf16x8*)&sA[abase + kc * 32];
            #pragma unroll
            for (int nt = 0; nt < 4; ++nt) {
                const bf16x8 bfr = *(const bf16x8*)&sWm[(nt * 16 + col) * 200 + kc * 32 + quad * 8];
                acc[nt] = __builtin_amdgcn_mfma_f32_16x16x32_bf16(af, bfr, acc[nt], 0, 0, 0);
            }
        }

        // epilogue: softplus, write msg (fp32, cached: k_node re-reads it),
        // bf16 msg into wave-private A2 overlay (stride 88)
        __bf16* A2 = &sA[wid * 16 * 200];
        #pragma unroll
        for (int nt = 0; nt < 4; ++nt) {
            #pragma unroll
            for (int rg = 0; rg < 4; ++rg) {
                const int row = quad * 4 + rg;
                const float sp = softplus_f(acc[nt][rg] + bm[nt]);
                out_msg[(size_t)(e0 + wid * 16 + row) * 64 + nt * 16 + col] = sp;
                A2[row * 88 + nt * 16 + col] = (__bf16)sp;
            }
        }
        // wave-private LDS: in-wave ds_write->ds_read ordering only; pin the
        // scheduler so the fragment reads stay after the writes (rule #18-ish).
        __builtin_amdgcn_sched_barrier(0);

        // ---- edge_new = msg @ We + b : 2 k-chunks x 4 n-tiles (We in regs) ----
        f32x4 acc2[4];
        #pragma unroll
        for (int nt = 0; nt < 4; ++nt) acc2[nt] = (f32x4){0.f, 0.f, 0.f, 0.f};
        #pragma unroll
        for (int kc = 0; kc < 2; ++kc) {
            const bf16x8 af = *(const bf16x8*)&A2[col * 88 + kc * 32 + quad * 8];
            #pragma unroll
            for (int nt = 0; nt < 4; ++nt)
                acc2[nt] = __builtin_amdgcn_mfma_f32_16x16x32_bf16(af, weF[kc][nt], acc2[nt], 0, 0, 0);
        }
        #pragma unroll
        for (int nt = 0; nt < 4; ++nt) {
            #pragma unroll
            for (int rg = 0; rg < 4; ++rg) {
                __builtin_nontemporal_store(   // single-use stream
                    acc2[nt][rg] + be[nt],
                    &out_edge[(size_t)(e0 + wid * 16 + quad * 4 + rg) * 64 + nt * 16 + col]);
            }
        }
        __syncthreads();   // protect sA before next tile's staging
    }
}

// ---------------- node kernel: mean-agg (CSR gather) + update GEMM ----------------
__global__ __launch_bounds__(256) void k_node(
    const float* __restrict__ x, const float* __restrict__ msg,
    const int* __restrict__ rowptr, const int* __restrict__ eidx,
    const float* __restrict__ Wupd, const float* __restrict__ bupd,
    float* __restrict__ out_x)
{
    __shared__ float sW[128 * 64];
    const int tid = threadIdx.x;
    for (int i = tid; i < 2048; i += 256)
        ((f32x4*)sW)[i] = ((const f32x4*)Wupd)[i];
    __syncthreads();

    const int lane = tid & 63, wid = tid >> 6;
    const float bu = bupd[lane];

    for (int n = blockIdx.x * 4 + wid; n < NN; n += gridDim.x * 4) {
        const int rs = rowptr[n], ren = rowptr[n + 1];

        float a0 = 0.f, a1 = 0.f, a2 = 0.f, a3 = 0.f;
        int j = rs;
        for (; j + 4 <= ren; j += 4) {
            const int e0 = eidx[j], e1 = eidx[j + 1], e2 = eidx[j + 2], e3 = eidx[j + 3];
            a0 += msg[(size_t)e0 * 64 + lane];
            a1 += msg[(size_t)e1 * 64 + lane];
            a2 += msg[(size_t)e2 * 64 + lane];
            a3 += msg[(size_t)e3 * 64 + lane];
        }
        for (; j < ren; ++j) a0 += msg[(size_t)eidx[j] * 64 + lane];
        const float acc  = (a0 + a1) + (a2 + a3);
        const float mean = acc / fmaxf((float)(ren - rs), 1.f);
        const float xr   = x[(size_t)n * 64 + lane];

        float o = bu;
        #pragma unroll 16
        for (int k = 0; k < 64; ++k)
            o += __shfl(xr, k) * sW[k * 64 + lane];
        #pragma unroll 16
        for (int k = 0; k < 64; ++k)
            o += __shfl(mean, k) * sW[(64 + k) * 64 + lane];

        out_x[(size_t)n * 64 + lane] = o;
    }
}

extern "C" void kernel_launch(void* const* d_in, const int* in_sizes, int n_in,
                              void* d_out, int out_size, void* d_ws, size_t ws_size,
                              hipStream_t stream) {
    const float* x     = (const float*)d_in[0];
    const int*   ei    = (const int*)d_in[1];
    const float* ea    = (const float*)d_in[2];
    const float* r2    = (const float*)d_in[3];
    const float* dinit = (const float*)d_in[4];
    const float* Wmsg  = (const float*)d_in[5];
    const float* bmsg  = (const float*)d_in[6];
    const float* Wupd  = (const float*)d_in[7];
    const float* bupd  = (const float*)d_in[8];
    const float* Wedge = (const float*)d_in[9];
    const float* bedge = (const float*)d_in[10];

    float* out_x      = (float*)d_out;                 // [50000,64]
    float* out_edge   = out_x + (size_t)NN * 64;       // [800000,64]
    float* out_msg    = out_edge + (size_t)NE * 64;    // [800000,64]
    float* out_strain = out_msg + (size_t)NE * 64;     // [800000,1]

    const size_t XB_BYTES  = (size_t)NN * 64 * 2;      // 6.4 MB, 16B-divisible
    const size_t CSR_INTS  = 50176 + 50304 + 50176 + 800000 + 256 + 256;
    const bool   use_xb    = ws_size >= XB_BYTES + CSR_INTS * 4 + 64;

    __bf16* xb  = (__bf16*)d_ws;
    int*    deg = use_xb ? (int*)((char*)d_ws + XB_BYTES) : (int*)d_ws;
    int* rowptr = deg + 50176;
    int* cursor = rowptr + 50304;
    int* eidx   = cursor + 50176;
    int* bsum   = eidx + 800000;
    int* boff   = bsum + 256;

    k_zero   <<<196,   256, 0, stream>>>(deg);
    k_hist   <<<3125,  256, 0, stream>>>(ei, deg);
    k_bsum   <<<196,   256, 0, stream>>>(deg, bsum);
    k_bscan  <<<1,     256, 0, stream>>>(bsum, boff);
    k_apply  <<<196,   256, 0, stream>>>(deg, boff, rowptr, cursor);
    k_scatter<<<3125,  256, 0, stream>>>(ei, cursor, eidx);
    if (use_xb) {
        k_prep        <<<3125, 256, 0, stream>>>(x, xb);
        k_edge<true>  <<<512,  512, 0, stream>>>(x, xb, ei, ea, r2, dinit, Wmsg, bmsg,
                                                 Wedge, bedge, out_edge, out_msg, out_strain);
    } else {
        k_edge<false> <<<512,  512, 0, stream>>>(x, nullptr, ei, ea, r2, dinit, Wmsg, bmsg,
                                                 Wedge, bedge, out_edge, out_msg, out_strain);
    }
    k_node   <<<2048,  256, 0, stream>>>(x, out_msg, rowptr, eidx, Wupd, bupd, out_x);
}

// Round 3
// 795.155 us; speedup vs baseline: 1.0034x; 1.0034x over previous
//
#include <hip/hip_runtime.h>
#include <math.h>

#define NN 50000
#define NE 800000
#define NTILE2 6250   // NE / 128
#define NBLK 196      // ceil(NN / 256)

typedef __bf16 bf16x4 __attribute__((ext_vector_type(4)));
typedef __bf16 bf16x8 __attribute__((ext_vector_type(8)));
typedef float  f32x4  __attribute__((ext_vector_type(4)));

// softplus via hw v_exp_f32 / v_log_f32
__device__ __forceinline__ float softplus_f(float v) {
    const float t = __expf(-fabsf(v));
    return fmaxf(v, 0.f) + __logf(1.f + t);
}

// ---------------- init: zero deg + zero agg + x fp32->bf16 ----------------
// 3125 x 256 threads = 800000 work items.
__global__ void k_init(const float* __restrict__ x, __bf16* __restrict__ xb,
                       int* __restrict__ deg, float* __restrict__ agg) {
    const int i = blockIdx.x * 256 + threadIdx.x;           // 0..799999
    if (i < NN * 16) {                                      // x: 800000 f32x4
        const f32x4 v = *(const f32x4*)(x + (size_t)i * 4);
        bf16x4 b;
        b[0]=(__bf16)v[0]; b[1]=(__bf16)v[1]; b[2]=(__bf16)v[2]; b[3]=(__bf16)v[3];
        *(bf16x4*)(xb + (size_t)i * 4) = b;
    }
    *(f32x4*)(agg + (size_t)i * 4) = (f32x4){0.f, 0.f, 0.f, 0.f};  // 3.2M floats
    if (i < NN) deg[i] = 0;
}

__global__ void k_hist(const int* __restrict__ ei, int* __restrict__ deg) {
    int e = blockIdx.x * blockDim.x + threadIdx.x;
    if (e < NE) atomicAdd(&deg[ei[NE + e]], 1);
}

// ---------------- edge kernel: strain + msg GEMM + agg atomics + edge GEMM --
// 512 threads / 128 edges per tile (8 waves x 16 edges), LDS 77.3KB ->
// 2 blocks/CU (16 waves/CU). Aggregation fused: msg values are atomically
// added into agg[dst][c] (global_atomic_add_f32 via unsafeAtomicAdd,
// fire-and-forget -- drains under edge GEMM + next staging). agg is 12.8MB
// -> L2/L3 resident. All output streams nontemporal (nothing re-reads them).
__global__ __launch_bounds__(512, 2) void k_edge_agg(
    const __bf16* __restrict__ xb, const int* __restrict__ ei,
    const float* __restrict__ ea, const float* __restrict__ r2,
    const float* __restrict__ dinit, const float* __restrict__ Wmsg,
    const float* __restrict__ bmsg, const float* __restrict__ Wedge,
    const float* __restrict__ bedge,
    float* __restrict__ out_edge, float* __restrict__ out_msg,
    float* __restrict__ out_strain, float* __restrict__ agg)
{
    __shared__ __bf16 sWm[64 * 200];    // Wmsg^T (k=0..191), row n, stride 200
    __shared__ __bf16 sA [128 * 200];   // 128 edge rows, stride 200
    __shared__ float  sStrain[128];

    const int tid  = threadIdx.x;
    const int lane = tid & 63;
    const int wid  = tid >> 6;     // wave 0..7, owns edges wid*16..wid*16+15
    const int col  = lane & 15;
    const int quad = lane >> 4;

    // ---- stage transposed Wmsg once per (persistent) block ----
    {
        const int n = tid & 63, kg = tid >> 6;
        for (int k = kg; k < 192; k += 8) {
            // original W rows: 0-63 x_j | 64-127 x_i | 128 strain | 129-192 ea
            float v = (k < 128) ? Wmsg[k * 64 + n] : Wmsg[(k + 1) * 64 + n];
            sWm[n * 200 + k] = (__bf16)v;
        }
    }
    // ---- Wedge^T B-fragments in registers (once per block) ----
    bf16x8 weF[2][4];
    #pragma unroll
    for (int kc = 0; kc < 2; ++kc)
        #pragma unroll
        for (int nt = 0; nt < 4; ++nt) {
            bf16x8 f;
            #pragma unroll
            for (int j = 0; j < 8; ++j)
                f[j] = (__bf16)Wedge[(kc * 32 + quad * 8 + j) * 64 + nt * 16 + col];
            weF[kc][nt] = f;
        }
    float bm[4], be[4], wst[4];
    #pragma unroll
    for (int nt = 0; nt < 4; ++nt) {
        bm[nt]  = bmsg[nt * 16 + col];
        be[nt]  = bedge[nt * 16 + col];
        wst[nt] = Wmsg[128 * 64 + nt * 16 + col];   // strain weight row (fp32)
    }

    for (int tile = blockIdx.x; tile < NTILE2; tile += gridDim.x) {
        const int e0 = tile * 128;

        // ---- stage x_src / x_dst (bf16 gathers; per-thread index loads) ----
        #pragma unroll
        for (int it = 0; it < 2; ++it) {
            const int i = tid + it * 512;     // 0..1023
            const int e = i >> 3, c = i & 7;  // 128 edges x 8 bf16x8-chunks
            const int s = ei[e0 + e], d = ei[NE + e0 + e];
            const bf16x8 vj = *(const bf16x8*)(xb + (size_t)s * 64 + c * 8);
            const bf16x8 vi = *(const bf16x8*)(xb + (size_t)d * 64 + c * 8);
            *(bf16x8*)&sA[e * 200 +      c * 8] = vj;
            *(bf16x8*)&sA[e * 200 + 64 + c * 8] = vi;
        }
        // ---- stage edge_attr (single-use stream: nontemporal) ----
        #pragma unroll
        for (int it = 0; it < 4; ++it) {
            const int i = tid + it * 512;      // 0..2047
            const int e = i >> 4, c = i & 15;
            const f32x4 ev = __builtin_nontemporal_load(
                                 (const f32x4*)(ea + (size_t)(e0 + e) * 64 + c * 4));
            bf16x4 d;
            d[0]=(__bf16)ev[0]; d[1]=(__bf16)ev[1]; d[2]=(__bf16)ev[2]; d[3]=(__bf16)ev[3];
            *(bf16x4*)&sA[e * 200 + 128 + c * 4] = d;
        }
        if (tid < 128) {
            const float rx = r2[(size_t)(e0 + tid) * 2];
            const float ry = r2[(size_t)(e0 + tid) * 2 + 1];
            const float di = dinit[e0 + tid];
            const float st = (sqrtf(rx * rx + ry * ry) - di) / di;
            sStrain[tid] = st;
            __builtin_nontemporal_store(st, &out_strain[e0 + tid]);
        }
        __syncthreads();

        // ---- msg = softplus(A @ Wm + strain*w128 + b): 6 k-chunks x 4 n-tiles
        f32x4 acc[4];
        const int r0 = wid * 16 + quad * 4;
        #pragma unroll
        for (int nt = 0; nt < 4; ++nt)
            #pragma unroll
            for (int rg = 0; rg < 4; ++rg)
                acc[nt][rg] = sStrain[r0 + rg] * wst[nt];   // rank-1 strain term

        const int abase = (wid * 16 + col) * 200 + quad * 8;
        #pragma unroll
        for (int kc = 0; kc < 6; ++kc) {
            const bf16x8 af = *(const bf16x8*)&sA[abase + kc * 32];
            #pragma unroll
            for (int nt = 0; nt < 4; ++nt) {
                const bf16x8 bfr = *(const bf16x8*)&sWm[(nt * 16 + col) * 200 + kc * 32 + quad * 8];
                acc[nt] = __builtin_amdgcn_mfma_f32_16x16x32_bf16(af, bfr, acc[nt], 0, 0, 0);
            }
        }

        // dst indices for this thread's 4 rows (16-lane broadcast loads)
        int dstv[4];
        #pragma unroll
        for (int rg = 0; rg < 4; ++rg)
            dstv[rg] = ei[NE + e0 + r0 + rg];

        // epilogue: softplus; nontemporal msg store; atomic agg scatter;
        // bf16 msg into wave-private A2 overlay (stride 88)
        __bf16* A2 = &sA[wid * 16 * 200];
        #pragma unroll
        for (int nt = 0; nt < 4; ++nt) {
            #pragma unroll
            for (int rg = 0; rg < 4; ++rg) {
                const int row = quad * 4 + rg;
                const float sp = softplus_f(acc[nt][rg] + bm[nt]);
                __builtin_nontemporal_store(
                    sp, &out_msg[(size_t)(e0 + wid * 16 + row) * 64 + nt * 16 + col]);
                unsafeAtomicAdd(&agg[(size_t)dstv[rg] * 64 + nt * 16 + col], sp);
                A2[row * 88 + nt * 16 + col] = (__bf16)sp;
            }
        }
        // wave-private LDS: pin fragment reads after the ds_writes
        __builtin_amdgcn_sched_barrier(0);

        // ---- edge_new = msg @ We + b : 2 k-chunks x 4 n-tiles (We in regs) ----
        f32x4 acc2[4];
        #pragma unroll
        for (int nt = 0; nt < 4; ++nt) acc2[nt] = (f32x4){0.f, 0.f, 0.f, 0.f};
        #pragma unroll
        for (int kc = 0; kc < 2; ++kc) {
            const bf16x8 af = *(const bf16x8*)&A2[col * 88 + kc * 32 + quad * 8];
            #pragma unroll
            for (int nt = 0; nt < 4; ++nt)
                acc2[nt] = __builtin_amdgcn_mfma_f32_16x16x32_bf16(af, weF[kc][nt], acc2[nt], 0, 0, 0);
        }
        #pragma unroll
        for (int nt = 0; nt < 4; ++nt) {
            #pragma unroll
            for (int rg = 0; rg < 4; ++rg) {
                __builtin_nontemporal_store(
                    acc2[nt][rg] + be[nt],
                    &out_edge[(size_t)(e0 + wid * 16 + quad * 4 + rg) * 64 + nt * 16 + col]);
            }
        }
        __syncthreads();   // protect sA before next tile's staging
    }
}

// ---------------- node kernel: pure streaming now (agg precomputed) --------
// read agg row + deg, mean, shuffle-GEMM with Wupd, write out_x.
__global__ __launch_bounds__(256) void k_node_lite(
    const float* __restrict__ x, const float* __restrict__ agg,
    const int* __restrict__ deg,
    const float* __restrict__ Wupd, const float* __restrict__ bupd,
    float* __restrict__ out_x)
{
    __shared__ float sW[128 * 64];
    const int tid = threadIdx.x;
    for (int i = tid; i < 2048; i += 256)
        ((f32x4*)sW)[i] = ((const f32x4*)Wupd)[i];
    __syncthreads();

    const int lane = tid & 63, wid = tid >> 6;
    const float bu = bupd[lane];

    for (int n = blockIdx.x * 4 + wid; n < NN; n += gridDim.x * 4) {
        const int d = deg[n];
        const float mean = agg[(size_t)n * 64 + lane] / fmaxf((float)d, 1.f);
        const float xr   = x[(size_t)n * 64 + lane];

        float o = bu;
        #pragma unroll 16
        for (int k = 0; k < 64; ++k)
            o += __shfl(xr, k) * sW[k * 64 + lane];
        #pragma unroll 16
        for (int k = 0; k < 64; ++k)
            o += __shfl(mean, k) * sW[(64 + k) * 64 + lane];

        out_x[(size_t)n * 64 + lane] = o;
    }
}

// ================= fallback path (ws too small): R1 CSR pipeline ===========
__global__ void k_zero(int* deg) {
    int i = blockIdx.x * blockDim.x + threadIdx.x;
    if (i < NN) deg[i] = 0;
}

__global__ void k_bsum(const int* __restrict__ deg, int* __restrict__ bsum) {
    __shared__ int ws4[4];
    const int tid = threadIdx.x;
    const int i = blockIdx.x * 256 + tid;
    int v = (i < NN) ? deg[i] : 0;
    #pragma unroll
    for (int off = 1; off < 64; off <<= 1) v += __shfl_xor(v, off);
    if ((tid & 63) == 0) ws4[tid >> 6] = v;
    __syncthreads();
    if (tid == 0) bsum[blockIdx.x] = ws4[0] + ws4[1] + ws4[2] + ws4[3];
}

__global__ void k_bscan(const int* __restrict__ bsum, int* __restrict__ boff) {
    __shared__ int wsum[4];
    const int tid = threadIdx.x, lane = tid & 63, wid = tid >> 6;
    const int v = (tid < NBLK) ? bsum[tid] : 0;
    int s = v;
    #pragma unroll
    for (int off = 1; off < 64; off <<= 1) {
        int t = __shfl_up(s, off);
        if (lane >= off) s += t;
    }
    if (lane == 63) wsum[wid] = s;
    __syncthreads();
    int add = 0;
    #pragma unroll
    for (int q = 0; q < 4; ++q) add += (q < wid) ? wsum[q] : 0;
    if (tid < NBLK) boff[tid] = (s + add) - v;
}

__global__ void k_apply(const int* __restrict__ deg, const int* __restrict__ boff,
                        int* __restrict__ rowptr, int* __restrict__ cursor) {
    __shared__ int wsum[4];
    const int tid = threadIdx.x, lane = tid & 63, wid = tid >> 6;
    const int i = blockIdx.x * 256 + tid;
    const int v = (i < NN) ? deg[i] : 0;
    int s = v;
    #pragma unroll
    for (int off = 1; off < 64; off <<= 1) {
        int t = __shfl_up(s, off);
        if (lane >= off) s += t;
    }
    if (lane == 63) wsum[wid] = s;
    __syncthreads();
    int add = boff[blockIdx.x];
    #pragma unroll
    for (int q = 0; q < 4; ++q) add += (q < wid) ? wsum[q] : 0;
    const int incl = s + add;
    if (i < NN) { rowptr[i + 1] = incl; cursor[i] = incl - v; }
    if (i == 0) rowptr[0] = 0;
}

__global__ void k_scatter(const int* __restrict__ ei, int* __restrict__ cursor,
                          int* __restrict__ eidx) {
    int e = blockIdx.x * blockDim.x + threadIdx.x;
    if (e < NE) {
        int d = ei[NE + e];
        int p = atomicAdd(&cursor[d], 1);
        eidx[p] = e;
    }
}

__global__ __launch_bounds__(512, 2) void k_edge_csr(
    const float* __restrict__ x, const int* __restrict__ ei,
    const float* __restrict__ ea, const float* __restrict__ r2,
    const float* __restrict__ dinit, const float* __restrict__ Wmsg,
    const float* __restrict__ bmsg, const float* __restrict__ Wedge,
    const float* __restrict__ bedge,
    float* __restrict__ out_edge, float* __restrict__ out_msg,
    float* __restrict__ out_strain)
{
    __shared__ __bf16 sWm[64 * 200];
    __shared__ __bf16 sA [128 * 200];
    __shared__ float  sStrain[128];

    const int tid  = threadIdx.x;
    const int lane = tid & 63;
    const int wid  = tid >> 6;
    const int col  = lane & 15;
    const int quad = lane >> 4;

    {
        const int n = tid & 63, kg = tid >> 6;
        for (int k = kg; k < 192; k += 8) {
            float v = (k < 128) ? Wmsg[k * 64 + n] : Wmsg[(k + 1) * 64 + n];
            sWm[n * 200 + k] = (__bf16)v;
        }
    }
    bf16x8 weF[2][4];
    #pragma unroll
    for (int kc = 0; kc < 2; ++kc)
        #pragma unroll
        for (int nt = 0; nt < 4; ++nt) {
            bf16x8 f;
            #pragma unroll
            for (int j = 0; j < 8; ++j)
                f[j] = (__bf16)Wedge[(kc * 32 + quad * 8 + j) * 64 + nt * 16 + col];
            weF[kc][nt] = f;
        }
    float bm[4], be[4], wst[4];
    #pragma unroll
    for (int nt = 0; nt < 4; ++nt) {
        bm[nt]  = bmsg[nt * 16 + col];
        be[nt]  = bedge[nt * 16 + col];
        wst[nt] = Wmsg[128 * 64 + nt * 16 + col];
    }

    for (int tile = blockIdx.x; tile < NTILE2; tile += gridDim.x) {
        const int e0 = tile * 128;
        #pragma unroll
        for (int it = 0; it < 4; ++it) {
            const int i = tid + it * 512;
            const int e = i >> 4, c = i & 15;
            const int s = ei[e0 + e], d = ei[NE + e0 + e];
            const f32x4 xj = *(const f32x4*)(x + (size_t)s * 64 + c * 4);
            const f32x4 xi = *(const f32x4*)(x + (size_t)d * 64 + c * 4);
            bf16x4 a, b;
            a[0]=(__bf16)xj[0]; a[1]=(__bf16)xj[1]; a[2]=(__bf16)xj[2]; a[3]=(__bf16)xj[3];
            b[0]=(__bf16)xi[0]; b[1]=(__bf16)xi[1]; b[2]=(__bf16)xi[2]; b[3]=(__bf16)xi[3];
            *(bf16x4*)&sA[e * 200 +      c * 4] = a;
            *(bf16x4*)&sA[e * 200 + 64 + c * 4] = b;
        }
        #pragma unroll
        for (int it = 0; it < 4; ++it) {
            const int i = tid + it * 512;
            const int e = i >> 4, c = i & 15;
            const f32x4 ev = __builtin_nontemporal_load(
                                 (const f32x4*)(ea + (size_t)(e0 + e) * 64 + c * 4));
            bf16x4 d;
            d[0]=(__bf16)ev[0]; d[1]=(__bf16)ev[1]; d[2]=(__bf16)ev[2]; d[3]=(__bf16)ev[3];
            *(bf16x4*)&sA[e * 200 + 128 + c * 4] = d;
        }
        if (tid < 128) {
            const float rx = r2[(size_t)(e0 + tid) * 2];
            const float ry = r2[(size_t)(e0 + tid) * 2 + 1];
            const float di = dinit[e0 + tid];
            const float st = (sqrtf(rx * rx + ry * ry) - di) / di;
            sStrain[tid] = st;
            __builtin_nontemporal_store(st, &out_strain[e0 + tid]);
        }
        __syncthreads();

        f32x4 acc[4];
        const int r0 = wid * 16 + quad * 4;
        #pragma unroll
        for (int nt = 0; nt < 4; ++nt)
            #pragma unroll
            for (int rg = 0; rg < 4; ++rg)
                acc[nt][rg] = sStrain[r0 + rg] * wst[nt];

        const int abase = (wid * 16 + col) * 200 + quad * 8;
        #pragma unroll
        for (int kc = 0; kc < 6; ++kc) {
            const bf16x8 af = *(const bf16x8*)&sA[abase + kc * 32];
            #pragma unroll
            for (int nt = 0; nt < 4; ++nt) {
                const bf16x8 bfr = *(const bf16x8*)&sWm[(nt * 16 + col) * 200 + kc * 32 + quad * 8];
                acc[nt] = __builtin_amdgcn_mfma_f32_16x16x32_bf16(af, bfr, acc[nt], 0, 0, 0);
            }
        }

        __bf16* A2 = &sA[wid * 16 * 200];
        #pragma unroll
        for (int nt = 0; nt < 4; ++nt) {
            #pragma unroll
            for (int rg = 0; rg < 4; ++rg) {
                const int row = quad * 4 + rg;
                const float sp = softplus_f(acc[nt][rg] + bm[nt]);
                out_msg[(size_t)(e0 + wid * 16 + row) * 64 + nt * 16 + col] = sp;
                A2[row * 88 + nt * 16 + col] = (__bf16)sp;
            }
        }
        __builtin_amdgcn_sched_barrier(0);

        f32x4 acc2[4];
        #pragma unroll
        for (int nt = 0; nt < 4; ++nt) acc2[nt] = (f32x4){0.f, 0.f, 0.f, 0.f};
        #pragma unroll
        for (int kc = 0; kc < 2; ++kc) {
            const bf16x8 af = *(const bf16x8*)&A2[col * 88 + kc * 32 + quad * 8];
            #pragma unroll
            for (int nt = 0; nt < 4; ++nt)
                acc2[nt] = __builtin_amdgcn_mfma_f32_16x16x32_bf16(af, weF[kc][nt], acc2[nt], 0, 0, 0);
        }
        #pragma unroll
        for (int nt = 0; nt < 4; ++nt) {
            #pragma unroll
            for (int rg = 0; rg < 4; ++rg) {
                __builtin_nontemporal_store(
                    acc2[nt][rg] + be[nt],
                    &out_edge[(size_t)(e0 + wid * 16 + quad * 4 + rg) * 64 + nt * 16 + col]);
            }
        }
        __syncthreads();
    }
}

__global__ __launch_bounds__(256) void k_node_csr(
    const float* __restrict__ x, const float* __restrict__ msg,
    const int* __restrict__ rowptr, const int* __restrict__ eidx,
    const float* __restrict__ Wupd, const float* __restrict__ bupd,
    float* __restrict__ out_x)
{
    __shared__ float sW[128 * 64];
    const int tid = threadIdx.x;
    for (int i = tid; i < 2048; i += 256)
        ((f32x4*)sW)[i] = ((const f32x4*)Wupd)[i];
    __syncthreads();

    const int lane = tid & 63, wid = tid >> 6;
    const float bu = bupd[lane];

    for (int n = blockIdx.x * 4 + wid; n < NN; n += gridDim.x * 4) {
        const int rs = rowptr[n], ren = rowptr[n + 1];
        float a0 = 0.f, a1 = 0.f, a2 = 0.f, a3 = 0.f;
        int j = rs;
        for (; j + 4 <= ren; j += 4) {
            const int e0 = eidx[j], e1 = eidx[j + 1], e2 = eidx[j + 2], e3 = eidx[j + 3];
            a0 += msg[(size_t)e0 * 64 + lane];
            a1 += msg[(size_t)e1 * 64 + lane];
            a2 += msg[(size_t)e2 * 64 + lane];
            a3 += msg[(size_t)e3 * 64 + lane];
        }
        for (; j < ren; ++j) a0 += msg[(size_t)eidx[j] * 64 + lane];
        const float acc  = (a0 + a1) + (a2 + a3);
        const float mean = acc / fmaxf((float)(ren - rs), 1.f);
        const float xr   = x[(size_t)n * 64 + lane];

        float o = bu;
        #pragma unroll 16
        for (int k = 0; k < 64; ++k)
            o += __shfl(xr, k) * sW[k * 64 + lane];
        #pragma unroll 16
        for (int k = 0; k < 64; ++k)
            o += __shfl(mean, k) * sW[(64 + k) * 64 + lane];

        out_x[(size_t)n * 64 + lane] = o;
    }
}

extern "C" void kernel_launch(void* const* d_in, const int* in_sizes, int n_in,
                              void* d_out, int out_size, void* d_ws, size_t ws_size,
                              hipStream_t stream) {
    const float* x     = (const float*)d_in[0];
    const int*   ei    = (const int*)d_in[1];
    const float* ea    = (const float*)d_in[2];
    const float* r2    = (const float*)d_in[3];
    const float* dinit = (const float*)d_in[4];
    const float* Wmsg  = (const float*)d_in[5];
    const float* bmsg  = (const float*)d_in[6];
    const float* Wupd  = (const float*)d_in[7];
    const float* bupd  = (const float*)d_in[8];
    const float* Wedge = (const float*)d_in[9];
    const float* bedge = (const float*)d_in[10];

    float* out_x      = (float*)d_out;                 // [50000,64]
    float* out_edge   = out_x + (size_t)NN * 64;       // [800000,64]
    float* out_msg    = out_edge + (size_t)NE * 64;    // [800000,64]
    float* out_strain = out_msg + (size_t)NE * 64;     // [800000,1]

    // new path workspace: xb (6.4MB) + agg (12.8MB) + deg (200KB)
    const size_t XB_BYTES  = (size_t)NN * 64 * 2;
    const size_t AGG_BYTES = (size_t)NN * 64 * 4 + (size_t)750000 * 16; // padded to 800000 f32x4 items
    const size_t DEG_BYTES = (size_t)NN * 4;
    const bool   use_agg   = ws_size >= XB_BYTES + AGG_BYTES + DEG_BYTES + 256;

    if (use_agg) {
        __bf16* xb  = (__bf16*)d_ws;
        float*  agg = (float*)((char*)d_ws + XB_BYTES);   // k_init zeros 800000 f32x4 = 12.8MB+pad
        int*    deg = (int*)((char*)d_ws + XB_BYTES + AGG_BYTES);

        k_init     <<<3125, 256, 0, stream>>>(x, xb, deg, agg);
        k_hist     <<<3125, 256, 0, stream>>>(ei, deg);
        k_edge_agg <<<512,  512, 0, stream>>>(xb, ei, ea, r2, dinit, Wmsg, bmsg,
                                              Wedge, bedge, out_edge, out_msg,
                                              out_strain, agg);
        k_node_lite<<<2048, 256, 0, stream>>>(x, agg, deg, Wupd, bupd, out_x);
    } else {
        int* deg    = (int*)d_ws;
        int* rowptr = deg + 50176;
        int* cursor = rowptr + 50304;
        int* eidx   = cursor + 50176;
        int* bsum   = eidx + 800000;
        int* boff   = bsum + 256;

        k_zero     <<<196,   256, 0, stream>>>(deg);
        k_hist     <<<3125,  256, 0, stream>>>(ei, deg);
        k_bsum     <<<196,   256, 0, stream>>>(deg, bsum);
        k_bscan    <<<1,     256, 0, stream>>>(bsum, boff);
        k_apply    <<<196,   256, 0, stream>>>(deg, boff, rowptr, cursor);
        k_scatter  <<<3125,  256, 0, stream>>>(ei, cursor, eidx);
        k_edge_csr <<<512,   512, 0, stream>>>(x, ei, ea, r2, dinit, Wmsg, bmsg,
                                               Wedge, bedge, out_edge, out_msg, out_strain);
        k_node_csr <<<2048,  256, 0, stream>>>(x, out_msg, rowptr, eidx, Wupd, bupd, out_x);
    }
}